// Round 2
// baseline (228.871 us; speedup 1.0000x reference)
//
#include <hip/hip_runtime.h>
#include <stdint.h>

#define D_MODEL 512
#define INNER   1024
#define NCAT    4096
#define BATCH   8
#define SEQ     2048
#define ROWS    (BATCH*SEQ)
#define LN_EPS  1e-5f
#define CHUNK   64
#define NCHUNK  (SEQ/CHUNK)

typedef unsigned short u16;
typedef unsigned int   u32;
typedef __attribute__((ext_vector_type(8))) short bf16x8;
typedef __attribute__((ext_vector_type(4))) float f32x4;

__device__ __forceinline__ u16 f2bf(float f) {
  u32 u = __builtin_bit_cast(u32, f);
  return (u16)((u + 0x7FFFu + ((u >> 16) & 1u)) >> 16);
}
__device__ __forceinline__ float bf2f(u32 lo) {
  return __builtin_bit_cast(float, lo << 16);
}
__device__ __forceinline__ float sigf(float x){ return 1.f/(1.f+__expf(-x)); }

__device__ __forceinline__ void glds16(const void* g, void* l) {
  __builtin_amdgcn_global_load_lds((const __attribute__((address_space(1))) void*)g,
                                   (__attribute__((address_space(3))) void*)l, 16, 0, 0);
}

// ---------------- LayerNorm: one wave per row of 512, write bf16 ----------------
__global__ __launch_bounds__(256) void ln_kernel(const float* __restrict__ x,
    const float* __restrict__ lw, const float* __restrict__ lb,
    u16* __restrict__ xn) {
  const int row  = blockIdx.x * 4 + (threadIdx.x >> 6);
  const int lane = threadIdx.x & 63;
  const float4* xr = (const float4*)(x + (size_t)row * D_MODEL);
  float4 v0 = xr[lane*2], v1 = xr[lane*2+1];
  float s  = v0.x+v0.y+v0.z+v0.w + v1.x+v1.y+v1.z+v1.w;
  float s2 = v0.x*v0.x+v0.y*v0.y+v0.z*v0.z+v0.w*v0.w
           + v1.x*v1.x+v1.y*v1.y+v1.z*v1.z+v1.w*v1.w;
  #pragma unroll
  for (int o=32;o;o>>=1){ s += __shfl_xor(s,o); s2 += __shfl_xor(s2,o); }
  const float mu = s * (1.f/D_MODEL);
  const float rs = rsqrtf(s2*(1.f/D_MODEL) - mu*mu + LN_EPS);
  const float4* wv = (const float4*)lw; const float4* bv = (const float4*)lb;
  float4 w0 = wv[lane*2], w1 = wv[lane*2+1];
  float4 b0 = bv[lane*2], b1 = bv[lane*2+1];
  u32 p0 = (u32)f2bf((v0.x-mu)*rs*w0.x+b0.x) | ((u32)f2bf((v0.y-mu)*rs*w0.y+b0.y)<<16);
  u32 p1 = (u32)f2bf((v0.z-mu)*rs*w0.z+b0.z) | ((u32)f2bf((v0.w-mu)*rs*w0.w+b0.w)<<16);
  u32 p2 = (u32)f2bf((v1.x-mu)*rs*w1.x+b1.x) | ((u32)f2bf((v1.y-mu)*rs*w1.y+b1.y)<<16);
  u32 p3 = (u32)f2bf((v1.z-mu)*rs*w1.z+b1.z) | ((u32)f2bf((v1.w-mu)*rs*w1.w+b1.w)<<16);
  ((uint4*)(xn + (size_t)row * D_MODEL))[lane] = make_uint4(p0,p1,p2,p3);
}

// ---------------- fp32 -> bf16 convert (weights) ----------------
__global__ void cvt_kernel(const float* __restrict__ s, u16* __restrict__ d, int n) {
  for (int i = blockIdx.x*blockDim.x+threadIdx.x; i < n; i += gridDim.x*blockDim.x)
    d[i] = f2bf(s[i]);
}

// ---------------- block swizzle: XCD-chunked (bijective, nwg%8==0) + GROUP_M=4 ----------------
__device__ __forceinline__ void sched_blk(int nbm, int nbn, int& bM, int& bN) {
  const int nwg = nbm * nbn;
  const int bid = blockIdx.x;
  const int cpx = nwg >> 3;
  const int swz = (bid & 7) * cpx + (bid >> 3);   // contiguous chunk per XCD
  const int grp = 4 * nbn;
  const int gm  = swz / grp;
  const int rem = swz - gm * grp;
  bM = gm * 4 + (rem & 3);
  bN = rem >> 2;
}

// ---------------- MFMA GEMM mainloop: 128x128 tile, BK=32, double-buffered LDS,
//                  counted vmcnt (never drains in steady state), raw barriers ----------------
// LDS: lA/lB each 2 x [128][32] u16 (8192 u16 = 16KB each, 32KB total)
__device__ __forceinline__ void gemm_main(const u16* __restrict__ A,
    const u16* __restrict__ Bm, int K, int nkt, int bM, int bN,
    u16* lA, u16* lB, f32x4 acc[4][4]) {
  const int tid = threadIdx.x;
  const u16* gA = A  + (size_t)(bM*128 + (tid>>2))*K + (tid&3)*8;
  const u16* gB = Bm + (size_t)(bN*128 + (tid>>2))*K + (tid&3)*8;
  u16* dA = lA + (tid>>2)*32 + (tid&3)*8;
  u16* dB = lB + (tid>>2)*32 + (tid&3)*8;
  const size_t rstep = (size_t)64*K;              // +64 rows in global

#define STAGE_T(koff, bufo) do { \
    const u16* sA = gA + (koff); const u16* sB = gB + (koff); \
    glds16(sA,         dA + (bufo));        glds16(sA + rstep, dA + (bufo) + 2048); \
    glds16(sB,         dB + (bufo));        glds16(sB + rstep, dB + (bufo) + 2048); \
  } while (0)

  STAGE_T(0, 0);        // tile 0 -> buf0
  STAGE_T(32, 4096);    // tile 1 -> buf1
  asm volatile("s_waitcnt vmcnt(4)" ::: "memory");   // tile 0 landed (mine)
  __builtin_amdgcn_s_barrier();                      // tile 0 landed (all waves)

  const int lane = tid & 63, wv = tid >> 6;
  const int wm = wv >> 1, wn = wv & 1;
  const int aoff = (wm*64 + (lane&15))*32 + (lane>>4)*8;
  const int boff = (wn*64 + (lane&15))*32 + (lane>>4)*8;

  for (int kt = 0; kt < nkt; ++kt) {
    const int cur = (kt & 1) << 12;                  // 0 / 4096
    bf16x8 af[4], bfr[4];
    #pragma unroll
    for (int m=0;m<4;m++) af[m]  = *(const bf16x8*)&lA[cur + aoff + m*512];
    #pragma unroll
    for (int n=0;n<4;n++) bfr[n] = *(const bf16x8*)&lB[cur + boff + n*512];
    asm volatile("s_waitcnt lgkmcnt(0)" ::: "memory");  // my reads of buf[cur] retired
    __builtin_amdgcn_sched_barrier(0);
    __builtin_amdgcn_s_barrier();                    // (a) all waves done reading buf[cur]
    if (kt + 2 < nkt) STAGE_T((kt+2)*32, cur);       // overwrite buf[cur] with tile kt+2
    #pragma unroll
    for (int m=0;m<4;m++)
      #pragma unroll
      for (int n=0;n<4;n++)
        acc[m][n] = __builtin_amdgcn_mfma_f32_16x16x32_bf16(af[m], bfr[n], acc[m][n], 0,0,0);
    if (kt + 2 < nkt) { asm volatile("s_waitcnt vmcnt(4)" ::: "memory"); }
    else              { asm volatile("s_waitcnt vmcnt(0)" ::: "memory"); }
    __builtin_amdgcn_s_barrier();                    // (b) tile kt+1 landed for all waves
  }
#undef STAGE_T
}

// ---------------- GEMM1: xn @ [in_proj_w; delta_w]^T, fused bias+activation split ----------------
__global__ __launch_bounds__(256, 2) void gemm1_kernel(const u16* __restrict__ A,
    const u16* __restrict__ Bm, const float* __restrict__ ipb,
    const float* __restrict__ db, u16* __restrict__ proj, u16* __restrict__ gate,
    u16* __restrict__ drive, u16* __restrict__ delta) {
  __shared__ u16 lA[8192], lB[8192];
  f32x4 acc[4][4];
  #pragma unroll
  for (int m=0;m<4;m++)
    #pragma unroll
    for (int n=0;n<4;n++) acc[m][n] = (f32x4){0.f,0.f,0.f,0.f};
  int bM, bN; sched_blk(ROWS/128, NCAT/128, bM, bN);
  gemm_main(A, Bm, D_MODEL, D_MODEL/32, bM, bN, lA, lB, acc);
  const int lane = threadIdx.x & 63, wv = threadIdx.x >> 6;
  const int wm = wv>>1, wn = wv&1;
  const int g = (bN*128) >> 10;                 // 0 proj, 1 gate, 2 drive, 3 delta
  u16* outp = (g==0)?proj:(g==1)?gate:(g==2)?drive:delta;
  #pragma unroll
  for (int n=0;n<4;n++) {
    const int col  = bN*128 + wn*64 + n*16 + (lane&15);
    const float bias = (col < 3072) ? ipb[col] : db[col-3072];
    const int lcol = col & (INNER-1);
    #pragma unroll
    for (int m=0;m<4;m++) {
      const int row0 = bM*128 + wm*64 + m*16 + ((lane>>4)<<2);
      #pragma unroll
      for (int r=0;r<4;r++) {
        float v = acc[m][n][r] + bias;
        float act;
        if (g==0)      act = v * sigf(v);                 // silu
        else if (g==1) act = sigf(v);                     // sigmoid gate
        else if (g==2) act = 2.f*sigf(2.f*v) - 1.f;       // tanh drive
        else           act = fmaxf(sigf(v), 1e-4f);       // delta
        outp[(size_t)(row0+r)*INNER + lcol] = f2bf(act);
      }
    }
  }
}

// ---------------- GEMM2: z @ out_proj_w^T + bias + residual (fp32 out) ----------------
__global__ __launch_bounds__(256, 2) void gemm2_kernel(const u16* __restrict__ A,
    const u16* __restrict__ Bm, const float* __restrict__ ob,
    const float* __restrict__ resid, float* __restrict__ out) {
  __shared__ u16 lA[8192], lB[8192];
  f32x4 acc[4][4];
  #pragma unroll
  for (int m=0;m<4;m++)
    #pragma unroll
    for (int n=0;n<4;n++) acc[m][n] = (f32x4){0.f,0.f,0.f,0.f};
  int bM, bN; sched_blk(ROWS/128, D_MODEL/128, bM, bN);
  gemm_main(A, Bm, INNER, INNER/32, bM, bN, lA, lB, acc);
  const int lane = threadIdx.x & 63, wv = threadIdx.x >> 6;
  const int wm = wv>>1, wn = wv&1;
  #pragma unroll
  for (int n=0;n<4;n++) {
    const int col = bN*128 + wn*64 + n*16 + (lane&15);
    const float bias = ob[col];
    #pragma unroll
    for (int m=0;m<4;m++) {
      const int row0 = bM*128 + wm*64 + m*16 + ((lane>>4)<<2);
      #pragma unroll
      for (int r=0;r<4;r++) {
        const size_t idx = (size_t)(row0+r)*D_MODEL + col;
        out[idx] = acc[m][n][r] + bias + resid[idx];
      }
    }
  }
}

// ---------------- scan pass 1: per-chunk local scan (zero init), save chunk-final ----------------
__global__ __launch_bounds__(256) void scan1_kernel(const u16* __restrict__ delta,
    const u16* __restrict__ drive, const float* __restrict__ sm,
    float* __restrict__ cS) {
  const int blk = blockIdx.x;
  const int half = blk & 1, ch = (blk>>1) & (NCHUNK-1), b = blk >> 6;
  const int c0 = half*512 + threadIdx.x*2;
  const float a0 = sigf(sm[c0]), a1 = sigf(sm[c0+1]);
  float s0 = 0.f, s1 = 0.f;
  size_t base = ((size_t)b*SEQ + ch*CHUNK)*INNER + c0;
  for (int t=0;t<CHUNK;t++) {
    u32 dl = *(const u32*)(delta + base);
    u32 dv = *(const u32*)(drive + base);
    s0 = a0*s0 + bf2f(dl & 0xffffu)*bf2f(dv & 0xffffu);
    s1 = a1*s1 + bf2f(dl >> 16)*bf2f(dv >> 16);
    base += INNER;
  }
  const size_t o = ((size_t)b*NCHUNK + ch)*INNER + c0;
  cS[o] = s0; cS[o+1] = s1;
}

// ---------------- scan pass 2: serial combine over 32 chunks -> exclusive carries ----------------
__global__ __launch_bounds__(256) void scan2_kernel(const float* __restrict__ sm,
    const float* __restrict__ cS, float* __restrict__ carry) {
  const int idx = blockIdx.x*256 + threadIdx.x;      // 0..4095
  const int b = idx >> 9, c0 = (idx & 511)*2;
  const float a0 = sigf(sm[c0]), a1 = sigf(sm[c0+1]);
  float A0 = a0, A1 = a1;
  #pragma unroll
  for (int i=0;i<6;i++){ A0*=A0; A1*=A1; }           // a^64 = a^CHUNK
  float cr0 = 0.f, cr1 = 0.f;
  for (int ch=0; ch<NCHUNK; ch++) {
    const size_t o = ((size_t)b*NCHUNK + ch)*INNER + c0;
    carry[o] = cr0; carry[o+1] = cr1;
    cr0 = A0*cr0 + cS[o];
    cr1 = A1*cr1 + cS[o+1];
  }
}

// ---------------- scan pass 3: finish scan + causal conv + gating -> z (bf16) ----------------
__global__ __launch_bounds__(256) void scan3_kernel(const u16* __restrict__ proj,
    const u16* __restrict__ gate, const u16* __restrict__ delta,
    const u16* __restrict__ drive, const float* __restrict__ carry,
    const float* __restrict__ sm, const float* __restrict__ cw,
    const float* __restrict__ cb, const float* __restrict__ sk,
    u16* __restrict__ z) {
  const int blk = blockIdx.x;
  const int half = blk & 1, ch = (blk>>1) & (NCHUNK-1), b = blk >> 6;
  const int c0 = half*512 + threadIdx.x*2;
  const float a0 = sigf(sm[c0]), a1 = sigf(sm[c0+1]);
  const float cb0 = cb[c0], cb1 = cb[c0+1];
  const float sk0 = sk[c0], sk1 = sk[c0+1];
  const float w00=cw[c0*4+0], w01=cw[c0*4+1], w02=cw[c0*4+2], w03=cw[c0*4+3];
  const float w10=cw[c0*4+4], w11=cw[c0*4+5], w12=cw[c0*4+6], w13=cw[c0*4+7];
  const size_t o = ((size_t)b*NCHUNK + ch)*INNER + c0;
  float s0 = carry[o], s1 = carry[o+1];
  const int t0 = ch*CHUNK;
  const size_t rowb = (size_t)b*SEQ*INNER + c0;
  float pa0=0,pb0=0,pc0=0, pa1=0,pb1=0,pc1=0;
  if (ch > 0) {
    u32 u3 = *(const u32*)(proj + rowb + (size_t)(t0-3)*INNER);
    u32 u2 = *(const u32*)(proj + rowb + (size_t)(t0-2)*INNER);
    u32 u1 = *(const u32*)(proj + rowb + (size_t)(t0-1)*INNER);
    pa0 = bf2f(u3&0xffffu); pa1 = bf2f(u3>>16);
    pb0 = bf2f(u2&0xffffu); pb1 = bf2f(u2>>16);
    pc0 = bf2f(u1&0xffffu); pc1 = bf2f(u1>>16);
  }
  size_t base = rowb + (size_t)t0*INNER;
  for (int t=0;t<CHUNK;t++) {
    u32 pu = *(const u32*)(proj + base);
    const float pd0 = bf2f(pu&0xffffu), pd1 = bf2f(pu>>16);
    const float co0 = w00*pa0 + w01*pb0 + w02*pc0 + w03*pd0 + cb0;
    const float co1 = w10*pa1 + w11*pb1 + w12*pc1 + w13*pd1 + cb1;
    pa0=pb0; pb0=pc0; pc0=pd0;  pa1=pb1; pb1=pc1; pc1=pd1;
    u32 dl = *(const u32*)(delta + base);
    u32 dv = *(const u32*)(drive + base);
    s0 = a0*s0 + bf2f(dl&0xffffu)*bf2f(dv&0xffffu);
    s1 = a1*s1 + bf2f(dl>>16)*bf2f(dv>>16);
    u32 gu = *(const u32*)(gate + base);
    const float z0 = (s0 + sk0*co0)*bf2f(gu&0xffffu);
    const float z1 = (s1 + sk1*co1)*bf2f(gu>>16);
    *(u32*)(z + base) = (u32)f2bf(z0) | ((u32)f2bf(z1)<<16);
    base += INNER;
  }
}

extern "C" void kernel_launch(void* const* d_in, const int* in_sizes, int n_in,
                              void* d_out, int out_size, void* d_ws, size_t ws_size,
                              hipStream_t stream) {
  const float* x    = (const float*)d_in[0];
  const float* ln_w = (const float*)d_in[1];
  const float* ln_b = (const float*)d_in[2];
  const float* ipw  = (const float*)d_in[3];
  const float* ipb  = (const float*)d_in[4];
  const float* cw   = (const float*)d_in[5];
  const float* cb   = (const float*)d_in[6];
  const float* dw   = (const float*)d_in[7];
  const float* db   = (const float*)d_in[8];
  const float* sm   = (const float*)d_in[9];
  const float* sk   = (const float*)d_in[10];
  const float* opw  = (const float*)d_in[11];
  const float* opb  = (const float*)d_in[12];
  float* out = (float*)d_out;

  uint8_t* w = (uint8_t*)d_ws;
  u16* xn    = (u16*)w;  w += (size_t)ROWS*D_MODEL*2;
  u16* wcat  = (u16*)w;  w += (size_t)NCAT*D_MODEL*2;
  u16* wout  = (u16*)w;  w += (size_t)D_MODEL*INNER*2;
  u16* proj  = (u16*)w;  w += (size_t)ROWS*INNER*2;
  u16* gate  = (u16*)w;  w += (size_t)ROWS*INNER*2;
  u16* drv   = (u16*)w;  w += (size_t)ROWS*INNER*2;
  u16* dlt   = (u16*)w;  w += (size_t)ROWS*INNER*2;
  u16* z     = (u16*)w;  w += (size_t)ROWS*INNER*2;
  float* cS    = (float*)w; w += (size_t)BATCH*NCHUNK*INNER*4;
  float* carry = (float*)w; w += (size_t)BATCH*NCHUNK*INNER*4;

  ln_kernel<<<ROWS/4, 256, 0, stream>>>(x, ln_w, ln_b, xn);
  cvt_kernel<<<2048, 256, 0, stream>>>(ipw, wcat, 3072*512);
  cvt_kernel<<<1024, 256, 0, stream>>>(dw, wcat + (size_t)3072*512, 1024*512);
  cvt_kernel<<<1024, 256, 0, stream>>>(opw, wout, 512*1024);
  gemm1_kernel<<<(ROWS/128)*(NCAT/128), 256, 0, stream>>>(xn, wcat, ipb, db, proj, gate, drv, dlt);
  scan1_kernel<<<BATCH*NCHUNK*2, 256, 0, stream>>>(dlt, drv, sm, cS);
  scan2_kernel<<<16, 256, 0, stream>>>(sm, cS, carry);
  scan3_kernel<<<BATCH*NCHUNK*2, 256, 0, stream>>>(proj, gate, dlt, drv, carry, sm, cw, cb, sk, z);
  gemm2_kernel<<<(ROWS/128)*(D_MODEL/128), 256, 0, stream>>>(z, wout, opb, x, out);
}

// Round 3
// 195.559 us; speedup vs baseline: 1.1703x; 1.1703x over previous
//
#include <hip/hip_runtime.h>
#include <stdint.h>

#define D_MODEL 512
#define INNER   1024
#define NCAT    4096
#define BATCH   8
#define SEQ     2048
#define ROWS    (BATCH*SEQ)
#define LN_EPS  1e-5f
#define CHUNK   64
#define NCHUNK  (SEQ/CHUNK)

typedef unsigned short u16;
typedef unsigned int   u32;
typedef __attribute__((ext_vector_type(8))) short bf16x8;
typedef __attribute__((ext_vector_type(4))) float f32x4;

__device__ __forceinline__ u16 f2bf(float f) {
  u32 u = __builtin_bit_cast(u32, f);
  return (u16)((u + 0x7FFFu + ((u >> 16) & 1u)) >> 16);
}
__device__ __forceinline__ float bf2f(u32 lo) {
  return __builtin_bit_cast(float, lo << 16);
}
__device__ __forceinline__ float sigf(float x){ return 1.f/(1.f+__expf(-x)); }

__device__ __forceinline__ void glds16(const void* g, void* l) {
  __builtin_amdgcn_global_load_lds((const __attribute__((address_space(1))) void*)g,
                                   (__attribute__((address_space(3))) void*)l, 16, 0, 0);
}

// ---------------- LayerNorm: one wave per row of 512, write bf16 ----------------
__global__ __launch_bounds__(256) void ln_kernel(const float* __restrict__ x,
    const float* __restrict__ lw, const float* __restrict__ lb,
    u16* __restrict__ xn) {
  const int row  = blockIdx.x * 4 + (threadIdx.x >> 6);
  const int lane = threadIdx.x & 63;
  const float4* xr = (const float4*)(x + (size_t)row * D_MODEL);
  float4 v0 = xr[lane*2], v1 = xr[lane*2+1];
  float s  = v0.x+v0.y+v0.z+v0.w + v1.x+v1.y+v1.z+v1.w;
  float s2 = v0.x*v0.x+v0.y*v0.y+v0.z*v0.z+v0.w*v0.w
           + v1.x*v1.x+v1.y*v1.y+v1.z*v1.z+v1.w*v1.w;
  #pragma unroll
  for (int o=32;o;o>>=1){ s += __shfl_xor(s,o); s2 += __shfl_xor(s2,o); }
  const float mu = s * (1.f/D_MODEL);
  const float rs = rsqrtf(s2*(1.f/D_MODEL) - mu*mu + LN_EPS);
  const float4* wv = (const float4*)lw; const float4* bv = (const float4*)lb;
  float4 w0 = wv[lane*2], w1 = wv[lane*2+1];
  float4 b0 = bv[lane*2], b1 = bv[lane*2+1];
  u32 p0 = (u32)f2bf((v0.x-mu)*rs*w0.x+b0.x) | ((u32)f2bf((v0.y-mu)*rs*w0.y+b0.y)<<16);
  u32 p1 = (u32)f2bf((v0.z-mu)*rs*w0.z+b0.z) | ((u32)f2bf((v0.w-mu)*rs*w0.w+b0.w)<<16);
  u32 p2 = (u32)f2bf((v1.x-mu)*rs*w1.x+b1.x) | ((u32)f2bf((v1.y-mu)*rs*w1.y+b1.y)<<16);
  u32 p3 = (u32)f2bf((v1.z-mu)*rs*w1.z+b1.z) | ((u32)f2bf((v1.w-mu)*rs*w1.w+b1.w)<<16);
  ((uint4*)(xn + (size_t)row * D_MODEL))[lane] = make_uint4(p0,p1,p2,p3);
}

// ---------------- fp32 -> bf16 convert (weights) ----------------
__global__ void cvt_kernel(const float* __restrict__ s, u16* __restrict__ d, int n) {
  for (int i = blockIdx.x*blockDim.x+threadIdx.x; i < n; i += gridDim.x*blockDim.x)
    d[i] = f2bf(s[i]);
}

// ---------------- block swizzle: XCD-chunked + L2-sized (GMxGN) groups ----------------
__device__ __forceinline__ void sched_blk(int nbm, int nbn, int GM, int GN,
                                          int& bM, int& bN) {
  const int nwg = nbm * nbn;
  const int bid = blockIdx.x;
  const int cpx = nwg >> 3;
  const int swz = (bid & 7) * cpx + (bid >> 3);   // contiguous chunk per XCD
  const int gsz = GM * GN;
  const int g   = swz / gsz, loc = swz - g * gsz;
  const int ngn = nbn / GN;
  const int gm  = g / ngn,  gn  = g - gm * ngn;
  bM = gm * GM + (loc % GM);
  bN = gn * GN + (loc / GM);
}

// ---------------- MFMA GEMM mainloop: 128x128 tile, BK=32, TRIPLE-buffered LDS,
// prefetch-2, counted vmcnt. Source-side permutes:
//  * k-seg XOR (seg ^ (ldsrow&3)) for A and B  -> conflict-free ds_read_b128
//  * B N-row permute (l -> (l&15)*4 + (l>>4) per 64-half) -> epilogue cols
//    (lane&15)*4+n are 4 CONSECUTIVE global cols (coalesced packed stores)
// LDS dest of global_load_lds stays linear (base + lane*16). ----------------
__device__ __forceinline__ void gemm_main(const u16* __restrict__ A,
    const u16* __restrict__ Bm, int K, int nkt, int bM, int bN,
    u16* lA, u16* lB, f32x4 acc[4][4]) {
  const int tid = threadIdx.x;
  const int l6  = tid >> 2;                        // LDS row (first 64-half)
  const int sg  = (tid & 3) ^ (l6 & 3);            // XOR-permuted k-seg
  const int pB  = (l6 & 15) * 4 + ((l6 >> 4) & 3); // B N-row permute
  const u16* gA = A  + (size_t)(bM*128 + l6)*K + sg*8;
  const u16* gB = Bm + (size_t)(bN*128 + pB)*K + sg*8;
  u16* dA = lA + tid*8;                            // linear dest, 16B/lane
  u16* dB = lB + tid*8;
  const size_t rstep = (size_t)64*K;               // +64 rows in global

#define STAGE_T(koff, bufo) do { \
    const u16* sA = gA + (koff); const u16* sB = gB + (koff); \
    glds16(sA,         dA + (bufo));        glds16(sA + rstep, dA + (bufo) + 2048); \
    glds16(sB,         dB + (bufo));        glds16(sB + rstep, dB + (bufo) + 2048); \
  } while (0)

  STAGE_T(0, 0);        // tile 0 -> buf0
  STAGE_T(32, 4096);    // tile 1 -> buf1
  asm volatile("s_waitcnt vmcnt(4)" ::: "memory");   // tile 0 landed (mine)
  __builtin_amdgcn_s_barrier();                      // tile 0 landed (all waves)

  const int lane = tid & 63, wv = tid >> 6;
  const int wm = wv >> 1, wn = wv & 1;
  const int kx = ((lane>>4) ^ (lane&3)) * 8;         // XOR-swizzled k-offset
  const int aoff = (wm*64 + (lane&15))*32 + kx;
  const int boff = (wn*64 + (lane&15))*32 + kx;

  int cur = 0, stg = 8192;
  for (int kt = 0; kt < nkt; ++kt) {
    bf16x8 af[4], bfr[4];
    #pragma unroll
    for (int m=0;m<4;m++) af[m]  = *(const bf16x8*)&lA[cur + aoff + m*512];
    #pragma unroll
    for (int n=0;n<4;n++) bfr[n] = *(const bf16x8*)&lB[cur + boff + n*512];
    asm volatile("s_waitcnt lgkmcnt(0)" ::: "memory");  // my reads retired
    __builtin_amdgcn_sched_barrier(0);
    __builtin_amdgcn_s_barrier();                    // (a) all waves done reading tile kt
    if (kt + 2 < nkt) STAGE_T((kt+2)*32, stg);       // stage tile kt+2 (buf read @ kt-1)
    #pragma unroll
    for (int m=0;m<4;m++)
      #pragma unroll
      for (int n=0;n<4;n++)
        acc[m][n] = __builtin_amdgcn_mfma_f32_16x16x32_bf16(af[m], bfr[n], acc[m][n], 0,0,0);
    if (kt + 2 < nkt) { asm volatile("s_waitcnt vmcnt(4)" ::: "memory"); }
    else              { asm volatile("s_waitcnt vmcnt(0)" ::: "memory"); }
    __builtin_amdgcn_s_barrier();                    // (b) tile kt+1 landed for all waves
    cur += 4096; if (cur == 12288) cur = 0;
    stg += 4096; if (stg == 12288) stg = 0;
  }
#undef STAGE_T
}

// ---------------- GEMM1: xn @ [in_proj_w; delta_w]^T, fused bias+activation ----------------
__global__ __launch_bounds__(256, 3) void gemm1_kernel(const u16* __restrict__ A,
    const u16* __restrict__ Bm, const float* __restrict__ ipb,
    const float* __restrict__ db, u16* __restrict__ proj, u16* __restrict__ gate,
    u16* __restrict__ drive, u16* __restrict__ delta) {
  __shared__ u16 lA[12288], lB[12288];
  f32x4 acc[4][4];
  #pragma unroll
  for (int m=0;m<4;m++)
    #pragma unroll
    for (int n=0;n<4;n++) acc[m][n] = (f32x4){0.f,0.f,0.f,0.f};
  int bM, bN; sched_blk(ROWS/128, NCAT/128, 16, 8, bM, bN);
  gemm_main(A, Bm, D_MODEL, D_MODEL/32, bM, bN, lA, lB, acc);
  const int lane = threadIdx.x & 63, wv = threadIdx.x >> 6;
  const int wm = wv>>1, wn = wv&1;
  const int g = (bN*128) >> 10;                 // 0 proj, 1 gate, 2 drive, 3 delta
  u16* outp = (g==0)?proj:(g==1)?gate:(g==2)?drive:delta;
  const int colb = bN*128 + wn*64 + (lane&15)*4;   // 4 consecutive global cols
  const float4 b4 = (colb < 3072) ? *(const float4*)&ipb[colb]
                                  : *(const float4*)&db[colb-3072];
  const float* bp = (const float*)&b4;
  const int lcolb = colb & (INNER-1);
  #pragma unroll
  for (int m=0;m<4;m++) {
    const int row0 = bM*128 + wm*64 + m*16 + ((lane>>4)<<2);
    #pragma unroll
    for (int r=0;r<4;r++) {
      float a[4];
      #pragma unroll
      for (int n=0;n<4;n++) {
        float v = acc[m][n][r] + bp[n];
        if (g==0)      a[n] = v * sigf(v);                 // silu
        else if (g==1) a[n] = sigf(v);                     // sigmoid gate
        else if (g==2) a[n] = 2.f*sigf(2.f*v) - 1.f;       // tanh drive
        else           a[n] = fmaxf(sigf(v), 1e-4f);       // delta
      }
      u32 lo = (u32)f2bf(a[0]) | ((u32)f2bf(a[1])<<16);
      u32 hi = (u32)f2bf(a[2]) | ((u32)f2bf(a[3])<<16);
      *(uint2*)&outp[(size_t)(row0+r)*INNER + lcolb] = make_uint2(lo, hi);
    }
  }
}

// ---------------- GEMM2: z @ out_proj_w^T + bias + residual (fp32 out) ----------------
__global__ __launch_bounds__(256, 3) void gemm2_kernel(const u16* __restrict__ A,
    const u16* __restrict__ Bm, const float* __restrict__ ob,
    const float* __restrict__ resid, float* __restrict__ out) {
  __shared__ u16 lA[12288], lB[12288];
  f32x4 acc[4][4];
  #pragma unroll
  for (int m=0;m<4;m++)
    #pragma unroll
    for (int n=0;n<4;n++) acc[m][n] = (f32x4){0.f,0.f,0.f,0.f};
  int bM, bN; sched_blk(ROWS/128, D_MODEL/128, 8, 4, bM, bN);
  gemm_main(A, Bm, INNER, INNER/32, bM, bN, lA, lB, acc);
  const int lane = threadIdx.x & 63, wv = threadIdx.x >> 6;
  const int wm = wv>>1, wn = wv&1;
  const int colb = bN*128 + wn*64 + (lane&15)*4;   // 4 consecutive global cols
  const float4 ob4 = *(const float4*)&ob[colb];
  #pragma unroll
  for (int m=0;m<4;m++) {
    const int row0 = bM*128 + wm*64 + m*16 + ((lane>>4)<<2);
    #pragma unroll
    for (int r=0;r<4;r++) {
      const size_t idx = (size_t)(row0+r)*D_MODEL + colb;
      float4 rs = *(const float4*)&resid[idx];
      float4 o;
      o.x = acc[m][0][r] + ob4.x + rs.x;
      o.y = acc[m][1][r] + ob4.y + rs.y;
      o.z = acc[m][2][r] + ob4.z + rs.z;
      o.w = acc[m][3][r] + ob4.w + rs.w;
      *(float4*)&out[idx] = o;
    }
  }
}

// ---------------- scan pass 1: per-chunk local scan (zero init), save chunk-final ----------------
__global__ __launch_bounds__(256) void scan1_kernel(const u16* __restrict__ delta,
    const u16* __restrict__ drive, const float* __restrict__ sm,
    float* __restrict__ cS) {
  const int blk = blockIdx.x;
  const int half = blk & 1, ch = (blk>>1) & (NCHUNK-1), b = blk >> 6;
  const int c0 = half*512 + threadIdx.x*2;
  const float a0 = sigf(sm[c0]), a1 = sigf(sm[c0+1]);
  float s0 = 0.f, s1 = 0.f;
  size_t base = ((size_t)b*SEQ + ch*CHUNK)*INNER + c0;
  for (int t=0;t<CHUNK;t++) {
    u32 dl = *(const u32*)(delta + base);
    u32 dv = *(const u32*)(drive + base);
    s0 = a0*s0 + bf2f(dl & 0xffffu)*bf2f(dv & 0xffffu);
    s1 = a1*s1 + bf2f(dl >> 16)*bf2f(dv >> 16);
    base += INNER;
  }
  const size_t o = ((size_t)b*NCHUNK + ch)*INNER + c0;
  cS[o] = s0; cS[o+1] = s1;
}

// ---------------- scan pass 2: serial combine over 32 chunks -> exclusive carries ----------------
__global__ __launch_bounds__(256) void scan2_kernel(const float* __restrict__ sm,
    const float* __restrict__ cS, float* __restrict__ carry) {
  const int idx = blockIdx.x*256 + threadIdx.x;      // 0..4095
  const int b = idx >> 9, c0 = (idx & 511)*2;
  const float a0 = sigf(sm[c0]), a1 = sigf(sm[c0+1]);
  float A0 = a0, A1 = a1;
  #pragma unroll
  for (int i=0;i<6;i++){ A0*=A0; A1*=A1; }           // a^64 = a^CHUNK
  float cr0 = 0.f, cr1 = 0.f;
  for (int ch=0; ch<NCHUNK; ch++) {
    const size_t o = ((size_t)b*NCHUNK + ch)*INNER + c0;
    carry[o] = cr0; carry[o+1] = cr1;
    cr0 = A0*cr0 + cS[o];
    cr1 = A1*cr1 + cS[o+1];
  }
}

// ---------------- scan pass 3: finish scan + causal conv + gating -> z (bf16) ----------------
__global__ __launch_bounds__(256) void scan3_kernel(const u16* __restrict__ proj,
    const u16* __restrict__ gate, const u16* __restrict__ delta,
    const u16* __restrict__ drive, const float* __restrict__ carry,
    const float* __restrict__ sm, const float* __restrict__ cw,
    const float* __restrict__ cb, const float* __restrict__ sk,
    u16* __restrict__ z) {
  const int blk = blockIdx.x;
  const int half = blk & 1, ch = (blk>>1) & (NCHUNK-1), b = blk >> 6;
  const int c0 = half*512 + threadIdx.x*2;
  const float a0 = sigf(sm[c0]), a1 = sigf(sm[c0+1]);
  const float cb0 = cb[c0], cb1 = cb[c0+1];
  const float sk0 = sk[c0], sk1 = sk[c0+1];
  const float w00=cw[c0*4+0], w01=cw[c0*4+1], w02=cw[c0*4+2], w03=cw[c0*4+3];
  const float w10=cw[c0*4+4], w11=cw[c0*4+5], w12=cw[c0*4+6], w13=cw[c0*4+7];
  const size_t o = ((size_t)b*NCHUNK + ch)*INNER + c0;
  float s0 = carry[o], s1 = carry[o+1];
  const int t0 = ch*CHUNK;
  const size_t rowb = (size_t)b*SEQ*INNER + c0;
  float pa0=0,pb0=0,pc0=0, pa1=0,pb1=0,pc1=0;
  if (ch > 0) {
    u32 u3 = *(const u32*)(proj + rowb + (size_t)(t0-3)*INNER);
    u32 u2 = *(const u32*)(proj + rowb + (size_t)(t0-2)*INNER);
    u32 u1 = *(const u32*)(proj + rowb + (size_t)(t0-1)*INNER);
    pa0 = bf2f(u3&0xffffu); pa1 = bf2f(u3>>16);
    pb0 = bf2f(u2&0xffffu); pb1 = bf2f(u2>>16);
    pc0 = bf2f(u1&0xffffu); pc1 = bf2f(u1>>16);
  }
  size_t base = rowb + (size_t)t0*INNER;
  for (int t=0;t<CHUNK;t++) {
    u32 pu = *(const u32*)(proj + base);
    const float pd0 = bf2f(pu&0xffffu), pd1 = bf2f(pu>>16);
    const float co0 = w00*pa0 + w01*pb0 + w02*pc0 + w03*pd0 + cb0;
    const float co1 = w10*pa1 + w11*pb1 + w12*pc1 + w13*pd1 + cb1;
    pa0=pb0; pb0=pc0; pc0=pd0;  pa1=pb1; pb1=pc1; pc1=pd1;
    u32 dl = *(const u32*)(delta + base);
    u32 dv = *(const u32*)(drive + base);
    s0 = a0*s0 + bf2f(dl&0xffffu)*bf2f(dv&0xffffu);
    s1 = a1*s1 + bf2f(dl>>16)*bf2f(dv>>16);
    u32 gu = *(const u32*)(gate + base);
    const float z0 = (s0 + sk0*co0)*bf2f(gu&0xffffu);
    const float z1 = (s1 + sk1*co1)*bf2f(gu>>16);
    *(u32*)(z + base) = (u32)f2bf(z0) | ((u32)f2bf(z1)<<16);
    base += INNER;
  }
}

extern "C" void kernel_launch(void* const* d_in, const int* in_sizes, int n_in,
                              void* d_out, int out_size, void* d_ws, size_t ws_size,
                              hipStream_t stream) {
  const float* x    = (const float*)d_in[0];
  const float* ln_w = (const float*)d_in[1];
  const float* ln_b = (const float*)d_in[2];
  const float* ipw  = (const float*)d_in[3];
  const float* ipb  = (const float*)d_in[4];
  const float* cw   = (const float*)d_in[5];
  const float* cb   = (const float*)d_in[6];
  const float* dw   = (const float*)d_in[7];
  const float* db   = (const float*)d_in[8];
  const float* sm   = (const float*)d_in[9];
  const float* sk   = (const float*)d_in[10];
  const float* opw  = (const float*)d_in[11];
  const float* opb  = (const float*)d_in[12];
  float* out = (float*)d_out;

  uint8_t* w = (uint8_t*)d_ws;
  u16* xn    = (u16*)w;  w += (size_t)ROWS*D_MODEL*2;
  u16* wcat  = (u16*)w;  w += (size_t)NCAT*D_MODEL*2;
  u16* wout  = (u16*)w;  w += (size_t)D_MODEL*INNER*2;
  u16* proj  = (u16*)w;  w += (size_t)ROWS*INNER*2;
  u16* gate  = (u16*)w;  w += (size_t)ROWS*INNER*2;
  u16* drv   = (u16*)w;  w += (size_t)ROWS*INNER*2;
  u16* dlt   = (u16*)w;  w += (size_t)ROWS*INNER*2;
  u16* z     = (u16*)w;  w += (size_t)ROWS*INNER*2;
  float* cS    = (float*)w; w += (size_t)BATCH*NCHUNK*INNER*4;
  float* carry = (float*)w; w += (size_t)BATCH*NCHUNK*INNER*4;

  ln_kernel<<<ROWS/4, 256, 0, stream>>>(x, ln_w, ln_b, xn);
  cvt_kernel<<<2048, 256, 0, stream>>>(ipw, wcat, 3072*512);
  cvt_kernel<<<1024, 256, 0, stream>>>(dw, wcat + (size_t)3072*512, 1024*512);
  cvt_kernel<<<1024, 256, 0, stream>>>(opw, wout, 512*1024);
  gemm1_kernel<<<(ROWS/128)*(NCAT/128), 256, 0, stream>>>(xn, wcat, ipb, db, proj, gate, drv, dlt);
  scan1_kernel<<<BATCH*NCHUNK*2, 256, 0, stream>>>(dlt, drv, sm, cS);
  scan2_kernel<<<16, 256, 0, stream>>>(sm, cS, carry);
  scan3_kernel<<<BATCH*NCHUNK*2, 256, 0, stream>>>(proj, gate, dlt, drv, carry, sm, cw, cb, sk, z);
  gemm2_kernel<<<(ROWS/128)*(D_MODEL/128), 256, 0, stream>>>(z, wout, opb, x, out);
}